// Round 1
// baseline (6585.397 us; speedup 1.0000x reference)
//
#include <hip/hip_runtime.h>
#include <math.h>

// ---------- helpers ----------
__device__ inline float bflo(unsigned w){ return __uint_as_float(w << 16); }
__device__ inline float bfhi(unsigned w){ return __uint_as_float(w & 0xffff0000u); }
__device__ inline unsigned short f2bf(float f){
  unsigned u = __float_as_uint(f);
  unsigned r = u + 0x7fffu + ((u >> 16) & 1u);
  return (unsigned short)(r >> 16);
}
__device__ inline unsigned ordered_key(float f){
  unsigned u = __float_as_uint(f);
  return (u & 0x80000000u) ? ~u : (u | 0x80000000u);
}
__device__ inline float unordered_key(unsigned k){
  unsigned u = (k & 0x80000000u) ? (k & 0x7fffffffu) : ~k;
  return __uint_as_float(u);
}
__device__ inline float fcomp(const float4& v, int k){
  return k==0 ? v.x : k==1 ? v.y : k==2 ? v.z : v.w;
}

// ---------- K0: convert weights to bf16 ----------
// wlr [128][256] (cols 0..127 = W_l, 128..255 = W_r), we [128][128], wmlp [256][128]
__global__ void k_convert(const float* __restrict__ Wl, const float* __restrict__ Wr,
                          const float* __restrict__ We, const float* __restrict__ Wmlp,
                          unsigned short* wlr, unsigned short* we, unsigned short* wmlp){
  int t = blockIdx.x * 256 + threadIdx.x;
  if (t < 128*256){
    int k = t >> 8, c = t & 255;
    float v = (c < 128) ? Wl[k*128 + c] : Wr[k*128 + (c - 128)];
    wlr[t]  = f2bf(v);
    wmlp[t] = f2bf(Wmlp[t]);   // 256*128 == 128*256 elements
  }
  if (t < 128*128) we[t] = f2bf(We[t]);
}

// ---------- K1: xl = x@W_l+b_l, xr = x@W_r+b_r  ->  xlxr [n][256] ----------
__launch_bounds__(256)
__global__ void k_node_linear(const float* __restrict__ x, const float* __restrict__ bl,
                              const float* __restrict__ br, const unsigned short* __restrict__ wlr,
                              float* __restrict__ xlxr, int n){
  __shared__ unsigned sW[64][128];  // 32KB: half-K x 128 col-pairs
  __shared__ float    sX[8][64];    // 2KB
  int t = threadIdx.x, cp = t & 127, g = t >> 7;   // 2 groups x 4 nodes
  int base = blockIdx.x * 8;
  float acc[4][2] = {{0.f,0.f},{0.f,0.f},{0.f,0.f},{0.f,0.f}};
  for (int kh = 0; kh < 2; ++kh){
    if (kh) __syncthreads();
    for (int i = t; i < 64*128; i += 256) sW[i>>7][i&127] = ((const unsigned*)wlr)[kh*8192 + i];
    for (int i = t; i < 8*64;  i += 256){
      int r = i >> 6, k = i & 63, nd = base + r;
      sX[r][k] = (nd < n) ? x[(size_t)nd*128 + kh*64 + k] : 0.f;
    }
    __syncthreads();
    for (int k4 = 0; k4 < 16; ++k4){
      float4 a0 = *(const float4*)&sX[g*4+0][k4*4];
      float4 a1 = *(const float4*)&sX[g*4+1][k4*4];
      float4 a2 = *(const float4*)&sX[g*4+2][k4*4];
      float4 a3 = *(const float4*)&sX[g*4+3][k4*4];
      #pragma unroll
      for (int kk = 0; kk < 4; ++kk){
        unsigned w = sW[k4*4+kk][cp];
        float w0 = bflo(w), w1 = bfhi(w);
        acc[0][0] = fmaf(fcomp(a0,kk), w0, acc[0][0]); acc[0][1] = fmaf(fcomp(a0,kk), w1, acc[0][1]);
        acc[1][0] = fmaf(fcomp(a1,kk), w0, acc[1][0]); acc[1][1] = fmaf(fcomp(a1,kk), w1, acc[1][1]);
        acc[2][0] = fmaf(fcomp(a2,kk), w0, acc[2][0]); acc[2][1] = fmaf(fcomp(a2,kk), w1, acc[2][1]);
        acc[3][0] = fmaf(fcomp(a3,kk), w0, acc[3][0]); acc[3][1] = fmaf(fcomp(a3,kk), w1, acc[3][1]);
      }
    }
  }
  int c0 = 2*cp;
  float b0 = (c0   < 128) ? bl[c0]   : br[c0-128];
  float b1 = (c0+1 < 128) ? bl[c0+1] : br[c0+1-128];
  #pragma unroll
  for (int i = 0; i < 4; ++i){
    int nd = base + g*4 + i;
    if (nd < n){
      float2 o; o.x = acc[i][0] + b0; o.y = acc[i][1] + b1;
      *(float2*)&xlxr[(size_t)nd*256 + c0] = o;
    }
  }
}

// ---------- K2: fused ee-GEMM + attention logits e[E][4] ----------
__launch_bounds__(256)
__global__ void k_edge_logits(const float* __restrict__ eattr, const int* __restrict__ src,
                              const int* __restrict__ dst, const unsigned short* __restrict__ we,
                              const float* __restrict__ be, const float* __restrict__ att,
                              const float* __restrict__ xlxr, float* __restrict__ elog, int E){
  __shared__ unsigned sW[128][64];  // 32KB
  __shared__ float    sA[16][128];  // 8KB
  int t = threadIdx.x, lane = t & 63, g = t >> 6;  // wave g handles 4 edges
  int base = blockIdx.x * 16;
  for (int i = t; i < 128*64; i += 256) sW[i>>6][i&63] = ((const unsigned*)we)[i];
  for (int i = t; i < 512; i += 256){
    int r = i >> 5, q = i & 31, e = base + r, ec = (e < E) ? e : E-1;
    *(float4*)&sA[r][q*4] = *(const float4*)&eattr[(size_t)ec*128 + q*4];
  }
  __syncthreads();
  float acc[4][2] = {{0.f,0.f},{0.f,0.f},{0.f,0.f},{0.f,0.f}};
  for (int k4 = 0; k4 < 32; ++k4){
    float4 a0 = *(const float4*)&sA[g*4+0][k4*4];
    float4 a1 = *(const float4*)&sA[g*4+1][k4*4];
    float4 a2 = *(const float4*)&sA[g*4+2][k4*4];
    float4 a3 = *(const float4*)&sA[g*4+3][k4*4];
    #pragma unroll
    for (int kk = 0; kk < 4; ++kk){
      unsigned w = sW[k4*4+kk][lane];
      float w0 = bflo(w), w1 = bfhi(w);
      acc[0][0] = fmaf(fcomp(a0,kk), w0, acc[0][0]); acc[0][1] = fmaf(fcomp(a0,kk), w1, acc[0][1]);
      acc[1][0] = fmaf(fcomp(a1,kk), w0, acc[1][0]); acc[1][1] = fmaf(fcomp(a1,kk), w1, acc[1][1]);
      acc[2][0] = fmaf(fcomp(a2,kk), w0, acc[2][0]); acc[2][1] = fmaf(fcomp(a2,kk), w1, acc[2][1]);
      acc[3][0] = fmaf(fcomp(a3,kk), w0, acc[3][0]); acc[3][1] = fmaf(fcomp(a3,kk), w1, acc[3][1]);
    }
  }
  int c0 = 2*lane;
  int h  = lane >> 4;
  float at0 = att[c0], at1 = att[c0+1];
  float be0 = be[c0],  be1 = be[c0+1];
  #pragma unroll
  for (int i = 0; i < 4; ++i){
    int e = base + g*4 + i;        // wave-uniform
    int ec = (e < E) ? e : E-1;
    int s_ = src[ec], d_ = dst[ec];
    float2 xlv = *(const float2*)&xlxr[(size_t)s_*256 + c0];
    float2 xrv = *(const float2*)&xlxr[(size_t)d_*256 + 128 + c0];
    float m0 = acc[i][0] + be0 + xlv.x + xrv.x;
    float m1 = acc[i][1] + be1 + xlv.y + xrv.y;
    m0 = (m0 > 0.f) ? m0 : 0.2f*m0;
    m1 = (m1 > 0.f) ? m1 : 0.2f*m1;
    float p = m0*at0 + m1*at1;
    #pragma unroll
    for (int o = 1; o < 16; o <<= 1) p += __shfl_xor(p, o);
    if ((lane & 15) == 0 && e < E) elog[(size_t)e*4 + h] = p;
  }
}

// ---------- K3: segment max via ordered-uint atomicMax ----------
__global__ void k_segmax(const float* __restrict__ elog, const int* __restrict__ dst,
                         unsigned* __restrict__ emaxk, int E){
  int t = blockIdx.x * 256 + threadIdx.x;
  if (t >= E*4) return;
  int e = t >> 2, h = t & 3;
  atomicMax(&emaxk[(size_t)dst[e]*4 + h], ordered_key(elog[t]));
}

// ---------- K4: ex = exp(e - emax[dst]); denom += ex ----------
__global__ void k_exp_denom(const float* __restrict__ elog, const int* __restrict__ dst,
                            const unsigned* __restrict__ emaxk, float* __restrict__ exv,
                            float* __restrict__ denom, int E){
  int t = blockIdx.x * 256 + threadIdx.x;
  if (t >= E*4) return;
  int e = t >> 2, h = t & 3, d_ = dst[e];
  unsigned k = emaxk[(size_t)d_*4 + h];
  float m = (k == 0u) ? 0.f : unordered_key(k);
  float ex = expf(elog[t] - m);
  exv[t] = ex;
  unsafeAtomicAdd(&denom[(size_t)d_*4 + h], ex);
}

// ---------- K5: agg[dst] += alpha * xl[src] ----------
__global__ void k_agg(const float* __restrict__ exv, const float* __restrict__ denom,
                      const int* __restrict__ src, const int* __restrict__ dst,
                      const float* __restrict__ xlxr, float* __restrict__ agg, int E){
  int t = blockIdx.x * 256 + threadIdx.x;
  int e = t >> 5, q = t & 31;
  if (e >= E) return;
  int s_ = src[e], d_ = dst[e];
  int h = q >> 3, c0 = q*4;
  float alpha = exv[(size_t)e*4 + h] / (denom[(size_t)d_*4 + h] + 1e-16f);
  float4 v = *(const float4*)&xlxr[(size_t)s_*256 + c0];
  float* a = &agg[(size_t)d_*128 + c0];
  unsafeAtomicAdd(a+0, alpha*v.x);
  unsafeAtomicAdd(a+1, alpha*v.y);
  unsafeAtomicAdd(a+2, alpha*v.z);
  unsafeAtomicAdd(a+3, alpha*v.w);
}

// ---------- K6: x_new = agg + bias ----------
__global__ void k_xnew(const float* __restrict__ agg, const float* __restrict__ bias,
                       float* __restrict__ out, int n){
  int t = blockIdx.x * 256 + threadIdx.x;
  int nd = t >> 5, q = t & 31;
  if (nd >= n) return;
  int c0 = q*4;
  float4 a = *(const float4*)&agg[(size_t)nd*128 + c0];
  float4 b = *(const float4*)&bias[c0];
  float4 o; o.x = a.x+b.x; o.y = a.y+b.y; o.z = a.z+b.z; o.w = a.w+b.w;
  *(float4*)&out[(size_t)nd*128 + c0] = o;
}

// ---------- K7: edge MLP: gather -> LN -> ReLU -> GEMM -> residual ----------
__launch_bounds__(256)
__global__ void k_edge_mlp(const float* __restrict__ xnew, const int* __restrict__ src,
                           const int* __restrict__ dst, const float* __restrict__ eattr,
                           const unsigned short* __restrict__ wmlp, const float* __restrict__ bmlp,
                           const float* __restrict__ lng, const float* __restrict__ lnb,
                           float* __restrict__ out, int E){
  __shared__ float    sH[16][256];  // 16KB
  __shared__ unsigned sW[128][64];  // 32KB (half of K at a time)
  int t = threadIdx.x, lane = t & 63, g = t >> 6;
  int base = blockIdx.x * 16;
  // gather concat rows
  for (int i = t; i < 1024; i += 256){
    int r = i >> 6, q = i & 63, e = base + r, ec = (e < E) ? e : E-1;
    int col = q*4;
    float4 v;
    if (col < 128) v = *(const float4*)&xnew[(size_t)src[ec]*128 + col];
    else           v = *(const float4*)&xnew[(size_t)dst[ec]*128 + (col-128)];
    *(float4*)&sH[r][col] = v;
  }
  __syncthreads();
  // LayerNorm + ReLU (16 threads per row)
  {
    int r = t >> 4, u = t & 15;
    float s = 0.f, ss = 0.f;
    #pragma unroll
    for (int j = 0; j < 16; ++j){ float v = sH[r][u + 16*j]; s += v; ss += v*v; }
    #pragma unroll
    for (int o = 1; o < 16; o <<= 1){ s += __shfl_xor(s, o); ss += __shfl_xor(ss, o); }
    float mean = s * (1.f/256.f);
    float var  = ss * (1.f/256.f) - mean*mean;
    float rstd = rsqrtf(var + 1e-5f);
    #pragma unroll
    for (int j = 0; j < 16; ++j){
      int c = u + 16*j;
      float v = (sH[r][c] - mean) * rstd * lng[c] + lnb[c];
      sH[r][c] = fmaxf(v, 0.f);
    }
  }
  __syncthreads();
  float acc[4][2] = {{0.f,0.f},{0.f,0.f},{0.f,0.f},{0.f,0.f}};
  for (int kh = 0; kh < 2; ++kh){
    if (kh) __syncthreads();
    for (int i = t; i < 128*64; i += 256) sW[i>>6][i&63] = ((const unsigned*)wmlp)[kh*8192 + i];
    __syncthreads();
    for (int k4 = 0; k4 < 32; ++k4){
      float4 a0 = *(const float4*)&sH[g*4+0][kh*128 + k4*4];
      float4 a1 = *(const float4*)&sH[g*4+1][kh*128 + k4*4];
      float4 a2 = *(const float4*)&sH[g*4+2][kh*128 + k4*4];
      float4 a3 = *(const float4*)&sH[g*4+3][kh*128 + k4*4];
      #pragma unroll
      for (int kk = 0; kk < 4; ++kk){
        unsigned w = sW[k4*4+kk][lane];
        float w0 = bflo(w), w1 = bfhi(w);
        acc[0][0] = fmaf(fcomp(a0,kk), w0, acc[0][0]); acc[0][1] = fmaf(fcomp(a0,kk), w1, acc[0][1]);
        acc[1][0] = fmaf(fcomp(a1,kk), w0, acc[1][0]); acc[1][1] = fmaf(fcomp(a1,kk), w1, acc[1][1]);
        acc[2][0] = fmaf(fcomp(a2,kk), w0, acc[2][0]); acc[2][1] = fmaf(fcomp(a2,kk), w1, acc[2][1]);
        acc[3][0] = fmaf(fcomp(a3,kk), w0, acc[3][0]); acc[3][1] = fmaf(fcomp(a3,kk), w1, acc[3][1]);
      }
    }
  }
  int c0 = 2*lane;
  float b0 = bmlp[c0], b1 = bmlp[c0+1];
  #pragma unroll
  for (int i = 0; i < 4; ++i){
    int e = base + g*4 + i;
    if (e < E){
      float2 ea = *(const float2*)&eattr[(size_t)e*128 + c0];
      float2 o; o.x = acc[i][0] + b0 + ea.x; o.y = acc[i][1] + b1 + ea.y;
      *(float2*)&out[(size_t)e*128 + c0] = o;
    }
  }
}

// ---------- launcher ----------
extern "C" void kernel_launch(void* const* d_in, const int* in_sizes, int n_in,
                              void* d_out, int out_size, void* d_ws, size_t ws_size,
                              hipStream_t stream){
  const float* x     = (const float*)d_in[0];
  const int*   eidx  = (const int*)  d_in[1];
  const float* eattr = (const float*)d_in[2];
  const float* Wl    = (const float*)d_in[3];
  const float* bl    = (const float*)d_in[4];
  const float* Wr    = (const float*)d_in[5];
  const float* br    = (const float*)d_in[6];
  const float* We    = (const float*)d_in[7];
  const float* be    = (const float*)d_in[8];
  const float* att   = (const float*)d_in[9];
  const float* bias  = (const float*)d_in[10];
  const float* lng   = (const float*)d_in[11];
  const float* lnb   = (const float*)d_in[12];
  const float* Wmlp  = (const float*)d_in[13];
  const float* bmlp  = (const float*)d_in[14];

  int n = in_sizes[0] / 128;
  int E = in_sizes[2] / 128;
  const int* src = eidx;
  const int* dst = eidx + E;

  char* ws = (char*)d_ws;
  size_t off = 0;
  float*    agg   = (float*)(ws + off);    off += (size_t)n*128*4;
  unsigned* emaxk = (unsigned*)(ws + off); off += (size_t)n*4*4;
  float*    denom = (float*)(ws + off);    off += (size_t)n*4*4;
  size_t zbytes = off;                      // contiguous zero region
  float*    xlxr  = (float*)(ws + off);    off += (size_t)n*256*4;
  float*    elog  = (float*)(ws + off);    off += (size_t)E*4*4;
  float*    exv   = (float*)(ws + off);    off += (size_t)E*4*4;
  unsigned short* wlr   = (unsigned short*)(ws + off); off += 128*256*2;
  unsigned short* wec   = (unsigned short*)(ws + off); off += 128*128*2;
  unsigned short* wmlpc = (unsigned short*)(ws + off); off += 256*128*2;

  float* xnew_out = (float*)d_out;
  float* eout     = (float*)d_out + (size_t)n*128;

  hipMemsetAsync(ws, 0, zbytes, stream);
  k_convert   <<<128, 256, 0, stream>>>(Wl, Wr, We, Wmlp, wlr, wec, wmlpc);
  k_node_linear<<<(n + 7)/8, 256, 0, stream>>>(x, bl, br, wlr, xlxr, n);
  k_edge_logits<<<(E + 15)/16, 256, 0, stream>>>(eattr, src, dst, wec, be, att, xlxr, elog, E);
  k_segmax    <<<((size_t)E*4 + 255)/256, 256, 0, stream>>>(elog, dst, emaxk, E);
  k_exp_denom <<<((size_t)E*4 + 255)/256, 256, 0, stream>>>(elog, dst, emaxk, exv, denom, E);
  k_agg       <<<((size_t)E*32 + 255)/256, 256, 0, stream>>>(exv, denom, src, dst, xlxr, agg, E);
  k_xnew      <<<((size_t)n*32 + 255)/256, 256, 0, stream>>>(agg, bias, xnew_out, n);
  k_edge_mlp  <<<(E + 15)/16, 256, 0, stream>>>(xnew_out, src, dst, eattr, wmlpc, bmlp, lng, lnb, eout, E);
}

// Round 2
// 1252.416 us; speedup vs baseline: 5.2582x; 5.2582x over previous
//
#include <hip/hip_runtime.h>
#include <math.h>

typedef float  f32x4  __attribute__((ext_vector_type(4)));
typedef __bf16 bf16x8 __attribute__((ext_vector_type(8)));

union FragU { uint4 q; bf16x8 b; };

__device__ inline float fc(const float4& v, int k){
  return k==0 ? v.x : k==1 ? v.y : k==2 ? v.z : v.w;
}
__device__ inline unsigned ordered_key(float f){
  unsigned u = __float_as_uint(f);
  return (u & 0x80000000u) ? ~u : (u | 0x80000000u);
}
__device__ inline float unordered_key(unsigned k){
  unsigned u = (k & 0x80000000u) ? (k & 0x7fffffffu) : ~k;
  return __uint_as_float(u);
}

// ---------- K0: pack weights to bf16 in MFMA B-fragment order ----------
// frag idx: (((ct*KS + ks)*64 + lane)*8 + j) ; k = ks*32 + (lane>>4)*8 + j ; c = ct*16 + (lane&15)
__global__ void k_pack(const float* __restrict__ Wl, const float* __restrict__ Wr,
                       const float* __restrict__ We, const float* __restrict__ Wm,
                       unsigned short* plr, unsigned short* pe, unsigned short* pm){
  int t = blockIdx.x * 256 + threadIdx.x;
  // wlr: K=128 (KS=4), N=256 (NT=16) -> 32768 elems
  if (t < 32768){
    int j = t & 7, lane = (t >> 3) & 63, ks = (t >> 9) & 3, ct = t >> 11;
    int k = ks*32 + (lane >> 4)*8 + j, c = ct*16 + (lane & 15);
    float v = (c < 128) ? Wl[k*128 + c] : Wr[k*128 + (c - 128)];
    __bf16 b = (__bf16)v; plr[t] = *(unsigned short*)&b;
  }
  // we: K=128 (KS=4), N=128 (NT=8) -> 16384 elems
  if (t < 16384){
    int j = t & 7, lane = (t >> 3) & 63, ks = (t >> 9) & 3, ct = t >> 11;
    int k = ks*32 + (lane >> 4)*8 + j, c = ct*16 + (lane & 15);
    __bf16 b = (__bf16)We[k*128 + c]; pe[t] = *(unsigned short*)&b;
  }
  // wmlp: K=256 (KS=8), N=128 (NT=8) -> 32768 elems
  if (t < 32768){
    int j = t & 7, lane = (t >> 3) & 63, ks = (t >> 9) & 7, ct = t >> 12;
    int k = ks*32 + (lane >> 4)*8 + j, c = ct*16 + (lane & 15);
    __bf16 b = (__bf16)Wm[k*128 + c]; pm[t] = *(unsigned short*)&b;
  }
}

// ---------- K1: xlxr = [x@W_l+b_l | x@W_r+b_r]  (MFMA) ----------
// 4 waves, 16 rows/wave -> 64 nodes/block. N=256 (16 col-tiles), K=128 (4 k-steps).
__launch_bounds__(256)
__global__ void k_node_linear(const float* __restrict__ x, const float* __restrict__ bl,
                              const float* __restrict__ br, const unsigned short* __restrict__ plr,
                              float* __restrict__ xlxr, int n){
  __shared__ uint4 sW[4096];  // 64KB packed bf16 frags
  int t = threadIdx.x, lane = t & 63, w = t >> 6, lo = lane & 15, hi = lane >> 4;
  for (int i = t; i < 4096; i += 256) sW[i] = ((const uint4*)plr)[i];
  int row = blockIdx.x*64 + w*16 + lo;
  int rc  = min(row, n-1);
  bf16x8 A[4];
  #pragma unroll
  for (int ks = 0; ks < 4; ++ks){
    const float* p = &x[(size_t)rc*128 + ks*32 + hi*8];
    float4 v0 = *(const float4*)p, v1 = *(const float4*)(p+4);
    FragU u;
    u.b[0]=(__bf16)v0.x; u.b[1]=(__bf16)v0.y; u.b[2]=(__bf16)v0.z; u.b[3]=(__bf16)v0.w;
    u.b[4]=(__bf16)v1.x; u.b[5]=(__bf16)v1.y; u.b[6]=(__bf16)v1.z; u.b[7]=(__bf16)v1.w;
    A[ks] = u.b;
  }
  __syncthreads();
  f32x4 acc[16];
  #pragma unroll
  for (int ct = 0; ct < 16; ++ct) acc[ct] = (f32x4)(0.f);
  #pragma unroll
  for (int ks = 0; ks < 4; ++ks){
    #pragma unroll
    for (int ct = 0; ct < 16; ++ct){
      FragU bu; bu.q = sW[(ct*4 + ks)*64 + lane];
      acc[ct] = __builtin_amdgcn_mfma_f32_16x16x32_bf16(A[ks], bu.b, acc[ct], 0, 0, 0);
    }
  }
  float biasL[16];
  #pragma unroll
  for (int ct = 0; ct < 16; ++ct){
    int c = ct*16 + lo;
    biasL[ct] = (c < 128) ? bl[c] : br[c - 128];
  }
  #pragma unroll
  for (int j = 0; j < 4; ++j){
    int nd = blockIdx.x*64 + w*16 + hi*4 + j;
    if (nd < n){
      #pragma unroll
      for (int ct = 0; ct < 16; ++ct)
        xlxr[(size_t)nd*256 + ct*16 + lo] = acc[ct][j] + biasL[ct];
    }
  }
}

// ---------- K2: ee GEMM (MFMA) + attention logits ----------
// 4 waves, 32 rows/wave -> 128 edges/block. N=128 (8 ct), K=128 (4 ks).
__launch_bounds__(256)
__global__ void k_edge_logits(const float* __restrict__ eattr, const int* __restrict__ src,
                              const int* __restrict__ dst, const unsigned short* __restrict__ pe,
                              const float* __restrict__ be, const float* __restrict__ att,
                              const float* __restrict__ xlxr, float* __restrict__ elog, int E){
  __shared__ uint4 sW[2048];  // 32KB
  int t = threadIdx.x, lane = t & 63, w = t >> 6, lo = lane & 15, hi = lane >> 4;
  for (int i = t; i < 2048; i += 256) sW[i] = ((const uint4*)pe)[i];
  int eb = blockIdx.x*128 + w*32;
  bf16x8 A[2][4];
  #pragma unroll
  for (int rt = 0; rt < 2; ++rt){
    int er = min(eb + rt*16 + lo, E-1);
    #pragma unroll
    for (int ks = 0; ks < 4; ++ks){
      const float* p = &eattr[(size_t)er*128 + ks*32 + hi*8];
      float4 v0 = *(const float4*)p, v1 = *(const float4*)(p+4);
      FragU u;
      u.b[0]=(__bf16)v0.x; u.b[1]=(__bf16)v0.y; u.b[2]=(__bf16)v0.z; u.b[3]=(__bf16)v0.w;
      u.b[4]=(__bf16)v1.x; u.b[5]=(__bf16)v1.y; u.b[6]=(__bf16)v1.z; u.b[7]=(__bf16)v1.w;
      A[rt][ks] = u.b;
    }
  }
  __syncthreads();
  f32x4 acc[2][8];
  #pragma unroll
  for (int rt = 0; rt < 2; ++rt)
    #pragma unroll
    for (int ct = 0; ct < 8; ++ct) acc[rt][ct] = (f32x4)(0.f);
  #pragma unroll
  for (int ks = 0; ks < 4; ++ks){
    #pragma unroll
    for (int ct = 0; ct < 8; ++ct){
      FragU bu; bu.q = sW[(ct*4 + ks)*64 + lane];
      acc[0][ct] = __builtin_amdgcn_mfma_f32_16x16x32_bf16(A[0][ks], bu.b, acc[0][ct], 0, 0, 0);
      acc[1][ct] = __builtin_amdgcn_mfma_f32_16x16x32_bf16(A[1][ks], bu.b, acc[1][ct], 0, 0, 0);
    }
  }
  float beL[8], atL[8];
  #pragma unroll
  for (int ct = 0; ct < 8; ++ct){ beL[ct] = be[ct*16 + lo]; atL[ct] = att[ct*16 + lo]; }
  #pragma unroll
  for (int rt = 0; rt < 2; ++rt){
    #pragma unroll
    for (int j = 0; j < 4; ++j){
      int e = eb + rt*16 + hi*4 + j;
      int ec = min(e, E-1);
      int s_ = src[ec], d_ = dst[ec];
      const float* xlp = &xlxr[(size_t)s_*256];
      const float* xrp = &xlxr[(size_t)d_*256 + 128];
      float qh[4];
      #pragma unroll
      for (int h = 0; h < 4; ++h){
        float p = 0.f;
        #pragma unroll
        for (int u = 0; u < 2; ++u){
          int ct = 2*h + u, c = ct*16 + lo;
          float m = acc[rt][ct][j] + beL[ct] + xlp[c] + xrp[c];
          m = (m > 0.f) ? m : 0.2f*m;
          p = fmaf(m, atL[ct], p);
        }
        p += __shfl_xor(p, 1); p += __shfl_xor(p, 2);
        p += __shfl_xor(p, 4); p += __shfl_xor(p, 8);
        qh[h] = p;
      }
      if (lo == 0 && e < E)
        *(float4*)&elog[(size_t)e*4] = make_float4(qh[0], qh[1], qh[2], qh[3]);
    }
  }
}

// ---------- K3: segment max via ordered-uint atomicMax ----------
__global__ void k_segmax(const float* __restrict__ elog, const int* __restrict__ dst,
                         unsigned* __restrict__ emaxk, int E){
  int t = blockIdx.x * 256 + threadIdx.x;
  if (t >= E*4) return;
  int e = t >> 2, h = t & 3;
  atomicMax(&emaxk[(size_t)dst[e]*4 + h], ordered_key(elog[t]));
}

// ---------- K4: ex = exp(e - emax[dst]); denom += ex ----------
__global__ void k_exp_denom(const float* __restrict__ elog, const int* __restrict__ dst,
                            const unsigned* __restrict__ emaxk, float* __restrict__ exv,
                            float* __restrict__ denom, int E){
  int t = blockIdx.x * 256 + threadIdx.x;
  if (t >= E*4) return;
  int e = t >> 2, h = t & 3, d_ = dst[e];
  unsigned k = emaxk[(size_t)d_*4 + h];
  float m = (k == 0u) ? 0.f : unordered_key(k);
  float ex = expf(elog[t] - m);
  exv[t] = ex;
  unsafeAtomicAdd(&denom[(size_t)d_*4 + h], ex);
}

// ---------- K5: agg[dst] += alpha * xl[src] ----------
__global__ void k_agg(const float* __restrict__ exv, const float* __restrict__ denom,
                      const int* __restrict__ src, const int* __restrict__ dst,
                      const float* __restrict__ xlxr, float* __restrict__ agg, int E){
  int t = blockIdx.x * 256 + threadIdx.x;
  int e = t >> 5, q = t & 31;
  if (e >= E) return;
  int s_ = src[e], d_ = dst[e];
  int h = q >> 3, c0 = q*4;
  float alpha = exv[(size_t)e*4 + h] / (denom[(size_t)d_*4 + h] + 1e-16f);
  float4 v = *(const float4*)&xlxr[(size_t)s_*256 + c0];
  float* a = &agg[(size_t)d_*128 + c0];
  unsafeAtomicAdd(a+0, alpha*v.x);
  unsafeAtomicAdd(a+1, alpha*v.y);
  unsafeAtomicAdd(a+2, alpha*v.z);
  unsafeAtomicAdd(a+3, alpha*v.w);
}

// ---------- K6: x_new = agg + bias ----------
__global__ void k_xnew(const float* __restrict__ agg, const float* __restrict__ bias,
                       float* __restrict__ out, int n){
  int t = blockIdx.x * 256 + threadIdx.x;
  int nd = t >> 5, q = t & 31;
  if (nd >= n) return;
  int c0 = q*4;
  float4 a = *(const float4*)&agg[(size_t)nd*128 + c0];
  float4 b = *(const float4*)&bias[c0];
  float4 o; o.x = a.x+b.x; o.y = a.y+b.y; o.z = a.z+b.z; o.w = a.w+b.w;
  *(float4*)&out[(size_t)nd*128 + c0] = o;
}

// ---------- K7: edge MLP (MFMA): gather -> in-register LN -> ReLU -> GEMM -> residual ----------
// 8 waves, 16 rows/wave -> 128 edges/block. N=128 (8 ct), K=256 (8 ks).
__launch_bounds__(512)
__global__ void k_edge_mlp(const float* __restrict__ xnew, const int* __restrict__ src,
                           const int* __restrict__ dst, const float* __restrict__ eattr,
                           const unsigned short* __restrict__ pm, const float* __restrict__ bmlp,
                           const float* __restrict__ lng, const float* __restrict__ lnb,
                           float* __restrict__ out, int E){
  __shared__ uint4 sW[4096];  // 64KB
  int t = threadIdx.x, lane = t & 63, w = t >> 6, lo = lane & 15, hi = lane >> 4;
  for (int i = t; i < 4096; i += 512) sW[i] = ((const uint4*)pm)[i];
  int e  = blockIdx.x*128 + w*16 + lo;
  int ec = min(e, E-1);
  int s_ = src[ec], d_ = dst[ec];
  const float* srow = &xnew[(size_t)s_*128];
  const float* drow = &xnew[(size_t)d_*128];
  // gather: lane owns row-lo cols {ks*32 + hi*8 + j}
  float raw[8][8];
  #pragma unroll
  for (int ks = 0; ks < 4; ++ks){
    const float* p = &srow[ks*32 + hi*8];
    float4 v0 = *(const float4*)p, v1 = *(const float4*)(p+4);
    raw[ks][0]=v0.x; raw[ks][1]=v0.y; raw[ks][2]=v0.z; raw[ks][3]=v0.w;
    raw[ks][4]=v1.x; raw[ks][5]=v1.y; raw[ks][6]=v1.z; raw[ks][7]=v1.w;
  }
  #pragma unroll
  for (int ks = 4; ks < 8; ++ks){
    const float* p = &drow[(ks-4)*32 + hi*8];
    float4 v0 = *(const float4*)p, v1 = *(const float4*)(p+4);
    raw[ks][0]=v0.x; raw[ks][1]=v0.y; raw[ks][2]=v0.z; raw[ks][3]=v0.w;
    raw[ks][4]=v1.x; raw[ks][5]=v1.y; raw[ks][6]=v1.z; raw[ks][7]=v1.w;
  }
  // in-register LayerNorm stats (row split across 4 lanes sharing lo)
  float s = 0.f, ss = 0.f;
  #pragma unroll
  for (int ks = 0; ks < 8; ++ks)
    #pragma unroll
    for (int j = 0; j < 8; ++j){ float v = raw[ks][j]; s += v; ss = fmaf(v, v, ss); }
  s  += __shfl_xor(s, 16);  s  += __shfl_xor(s, 32);
  ss += __shfl_xor(ss, 16); ss += __shfl_xor(ss, 32);
  float mean = s * (1.f/256.f);
  float var  = ss * (1.f/256.f) - mean*mean;
  float rstd = rsqrtf(var + 1e-5f);
  // normalize + affine + relu -> bf16 A-frags
  bf16x8 A[8];
  #pragma unroll
  for (int ks = 0; ks < 8; ++ks){
    int cb = ks*32 + hi*8;
    float4 ga = *(const float4*)&lng[cb], gb = *(const float4*)&lng[cb+4];
    float4 ba = *(const float4*)&lnb[cb], bb = *(const float4*)&lnb[cb+4];
    FragU u;
    #pragma unroll
    for (int j = 0; j < 4; ++j){
      float v = fmaxf(fmaf((raw[ks][j] - mean)*rstd, fc(ga,j), fc(ba,j)), 0.f);
      u.b[j] = (__bf16)v;
    }
    #pragma unroll
    for (int j = 0; j < 4; ++j){
      float v = fmaxf(fmaf((raw[ks][j+4] - mean)*rstd, fc(gb,j), fc(bb,j)), 0.f);
      u.b[j+4] = (__bf16)v;
    }
    A[ks] = u.b;
  }
  __syncthreads();
  f32x4 acc[8];
  #pragma unroll
  for (int ct = 0; ct < 8; ++ct) acc[ct] = (f32x4)(0.f);
  #pragma unroll
  for (int ks = 0; ks < 8; ++ks){
    #pragma unroll
    for (int ct = 0; ct < 8; ++ct){
      FragU bu; bu.q = sW[(ct*8 + ks)*64 + lane];
      acc[ct] = __builtin_amdgcn_mfma_f32_16x16x32_bf16(A[ks], bu.b, acc[ct], 0, 0, 0);
    }
  }
  float bmL[8];
  #pragma unroll
  for (int ct = 0; ct < 8; ++ct) bmL[ct] = bmlp[ct*16 + lo];
  #pragma unroll
  for (int j = 0; j < 4; ++j){
    int e2 = blockIdx.x*128 + w*16 + hi*4 + j;
    if (e2 < E){
      #pragma unroll
      for (int ct = 0; ct < 8; ++ct){
        int c = ct*16 + lo;
        out[(size_t)e2*128 + c] = acc[ct][j] + bmL[ct] + eattr[(size_t)e2*128 + c];
      }
    }
  }
}

// ---------- launcher ----------
extern "C" void kernel_launch(void* const* d_in, const int* in_sizes, int n_in,
                              void* d_out, int out_size, void* d_ws, size_t ws_size,
                              hipStream_t stream){
  const float* x     = (const float*)d_in[0];
  const int*   eidx  = (const int*)  d_in[1];
  const float* eattr = (const float*)d_in[2];
  const float* Wl    = (const float*)d_in[3];
  const float* bl    = (const float*)d_in[4];
  const float* Wr    = (const float*)d_in[5];
  const float* br    = (const float*)d_in[6];
  const float* We    = (const float*)d_in[7];
  const float* be    = (const float*)d_in[8];
  const float* att   = (const float*)d_in[9];
  const float* bias  = (const float*)d_in[10];
  const float* lng   = (const float*)d_in[11];
  const float* lnb   = (const float*)d_in[12];
  const float* Wmlp  = (const float*)d_in[13];
  const float* bmlp  = (const float*)d_in[14];

  int n = in_sizes[0] / 128;
  int E = in_sizes[2] / 128;
  const int* src = eidx;
  const int* dst = eidx + E;

  char* ws = (char*)d_ws;
  size_t off = 0;
  float*    agg   = (float*)(ws + off);    off += (size_t)n*128*4;
  unsigned* emaxk = (unsigned*)(ws + off); off += (size_t)n*4*4;
  float*    denom = (float*)(ws + off);    off += (size_t)n*4*4;
  size_t zbytes = off;                      // contiguous zero region
  float*    xlxr  = (float*)(ws + off);    off += (size_t)n*256*4;
  float*    elog  = (float*)(ws + off);    off += (size_t)E*4*4;
  float*    exv   = (float*)(ws + off);    off += (size_t)E*4*4;
  unsigned short* plr = (unsigned short*)(ws + off); off += 32768*2;
  unsigned short* pe  = (unsigned short*)(ws + off); off += 16384*2;
  unsigned short* pm  = (unsigned short*)(ws + off); off += 32768*2;

  float* xnew_out = (float*)d_out;
  float* eout     = (float*)d_out + (size_t)n*128;

  hipMemsetAsync(ws, 0, zbytes, stream);
  k_pack       <<<128, 256, 0, stream>>>(Wl, Wr, We, Wmlp, plr, pe, pm);
  k_node_linear<<<(n + 63)/64, 256, 0, stream>>>(x, bl, br, plr, xlxr, n);
  k_edge_logits<<<(E + 127)/128, 256, 0, stream>>>(eattr, src, dst, pe, be, att, xlxr, elog, E);
  k_segmax     <<<((size_t)E*4 + 255)/256, 256, 0, stream>>>(elog, dst, emaxk, E);
  k_exp_denom  <<<((size_t)E*4 + 255)/256, 256, 0, stream>>>(elog, dst, emaxk, exv, denom, E);
  k_agg        <<<((size_t)E*32 + 255)/256, 256, 0, stream>>>(exv, denom, src, dst, xlxr, agg, E);
  k_xnew       <<<((size_t)n*32 + 255)/256, 256, 0, stream>>>(agg, bias, xnew_out, n);
  k_edge_mlp   <<<(E + 127)/128, 512, 0, stream>>>(xnew_out, src, dst, eattr, pm, bmlp, lng, lnb, eout, E);
}

// Round 3
// 669.709 us; speedup vs baseline: 9.8332x; 1.8701x over previous
//
#include <hip/hip_runtime.h>
#include <math.h>

typedef float  f32x4  __attribute__((ext_vector_type(4)));
typedef __bf16 bf16x8 __attribute__((ext_vector_type(8)));

union FragU { uint4 q; bf16x8 b; };

__device__ inline float fc(const float4& v, int k){
  return k==0 ? v.x : k==1 ? v.y : k==2 ? v.z : v.w;
}

// ---------- K0: pack weights to bf16 in MFMA B-fragment order ----------
// frag idx: (((ct*KS + ks)*64 + lane)*8 + j) ; k = ks*32 + (lane>>4)*8 + j ; c = ct*16 + (lane&15)
__global__ void k_pack(const float* __restrict__ Wl, const float* __restrict__ Wr,
                       const float* __restrict__ We, const float* __restrict__ Wm,
                       unsigned short* plr, unsigned short* pe, unsigned short* pm){
  int t = blockIdx.x * 256 + threadIdx.x;
  if (t < 32768){
    int j = t & 7, lane = (t >> 3) & 63, ks = (t >> 9) & 3, ct = t >> 11;
    int k = ks*32 + (lane >> 4)*8 + j, c = ct*16 + (lane & 15);
    float v = (c < 128) ? Wl[k*128 + c] : Wr[k*128 + (c - 128)];
    __bf16 b = (__bf16)v; plr[t] = *(unsigned short*)&b;
  }
  if (t < 16384){
    int j = t & 7, lane = (t >> 3) & 63, ks = (t >> 9) & 3, ct = t >> 11;
    int k = ks*32 + (lane >> 4)*8 + j, c = ct*16 + (lane & 15);
    __bf16 b = (__bf16)We[k*128 + c]; pe[t] = *(unsigned short*)&b;
  }
  if (t < 32768){
    int j = t & 7, lane = (t >> 3) & 63, ks = (t >> 9) & 7, ct = t >> 12;
    int k = ks*32 + (lane >> 4)*8 + j, c = ct*16 + (lane & 15);
    __bf16 b = (__bf16)Wm[k*128 + c]; pm[t] = *(unsigned short*)&b;
  }
}

// ---------- CSR build: histogram -> scan -> scatter ----------
__global__ void k_hist(const int* __restrict__ dst, int* __restrict__ cnt, int E){
  int e = blockIdx.x*256 + threadIdx.x;
  if (e < E) atomicAdd(&cnt[dst[e]], 1);
}

// single block, 1024 threads, 8 elems/thread per chunk
__global__ void k_scan(const int* __restrict__ cnt, int* __restrict__ rowptr,
                       int* __restrict__ cursor, int n){
  __shared__ int sums[1024];
  __shared__ int carry_s;
  int t = threadIdx.x;
  if (t == 0) carry_s = 0;
  __syncthreads();
  for (int base = 0; base < n; base += 8192){
    int v[8]; int loc = 0;
    #pragma unroll
    for (int j = 0; j < 8; ++j){
      int i = base + t*8 + j;
      v[j] = (i < n) ? cnt[i] : 0; loc += v[j];
    }
    sums[t] = loc; __syncthreads();
    for (int off = 1; off < 1024; off <<= 1){
      int val = (t >= off) ? sums[t-off] : 0;
      __syncthreads();
      sums[t] += val;
      __syncthreads();
    }
    int carry = carry_s;
    int excl = carry + sums[t] - loc;
    #pragma unroll
    for (int j = 0; j < 8; ++j){
      int i = base + t*8 + j;
      if (i < n){ rowptr[i] = excl; cursor[i] = excl; }
      excl += v[j];
    }
    __syncthreads();
    if (t == 1023) carry_s = carry + sums[1023];
    __syncthreads();
  }
  if (t == 0) rowptr[n] = carry_s;
}

__global__ void k_scatter(const int* __restrict__ dst, int* __restrict__ cursor,
                          int* __restrict__ eids, int E){
  int e = blockIdx.x*256 + threadIdx.x;
  if (e < E){ int p = atomicAdd(&cursor[dst[e]], 1); eids[p] = e; }
}

// ---------- K1: xlxr = [x@W_l+b_l | x@W_r+b_r]  (MFMA) ----------
__launch_bounds__(256)
__global__ void k_node_linear(const float* __restrict__ x, const float* __restrict__ bl,
                              const float* __restrict__ br, const unsigned short* __restrict__ plr,
                              float* __restrict__ xlxr, int n){
  __shared__ uint4 sW[4096];
  int t = threadIdx.x, lane = t & 63, w = t >> 6, lo = lane & 15, hi = lane >> 4;
  for (int i = t; i < 4096; i += 256) sW[i] = ((const uint4*)plr)[i];
  int row = blockIdx.x*64 + w*16 + lo;
  int rc  = min(row, n-1);
  bf16x8 A[4];
  #pragma unroll
  for (int ks = 0; ks < 4; ++ks){
    const float* p = &x[(size_t)rc*128 + ks*32 + hi*8];
    float4 v0 = *(const float4*)p, v1 = *(const float4*)(p+4);
    FragU u;
    u.b[0]=(__bf16)v0.x; u.b[1]=(__bf16)v0.y; u.b[2]=(__bf16)v0.z; u.b[3]=(__bf16)v0.w;
    u.b[4]=(__bf16)v1.x; u.b[5]=(__bf16)v1.y; u.b[6]=(__bf16)v1.z; u.b[7]=(__bf16)v1.w;
    A[ks] = u.b;
  }
  __syncthreads();
  f32x4 acc[16];
  #pragma unroll
  for (int ct = 0; ct < 16; ++ct) acc[ct] = (f32x4)(0.f);
  #pragma unroll
  for (int ks = 0; ks < 4; ++ks){
    #pragma unroll
    for (int ct = 0; ct < 16; ++ct){
      FragU bu; bu.q = sW[(ct*4 + ks)*64 + lane];
      acc[ct] = __builtin_amdgcn_mfma_f32_16x16x32_bf16(A[ks], bu.b, acc[ct], 0, 0, 0);
    }
  }
  float biasL[16];
  #pragma unroll
  for (int ct = 0; ct < 16; ++ct){
    int c = ct*16 + lo;
    biasL[ct] = (c < 128) ? bl[c] : br[c - 128];
  }
  #pragma unroll
  for (int j = 0; j < 4; ++j){
    int nd = blockIdx.x*64 + w*16 + hi*4 + j;
    if (nd < n){
      #pragma unroll
      for (int ct = 0; ct < 16; ++ct)
        xlxr[(size_t)nd*256 + ct*16 + lo] = acc[ct][j] + biasL[ct];
    }
  }
}

// ---------- K2: ee GEMM (MFMA) + attention logits ----------
__launch_bounds__(256)
__global__ void k_edge_logits(const float* __restrict__ eattr, const int* __restrict__ src,
                              const int* __restrict__ dst, const unsigned short* __restrict__ pe,
                              const float* __restrict__ be, const float* __restrict__ att,
                              const float* __restrict__ xlxr, float* __restrict__ elog, int E){
  __shared__ uint4 sW[2048];
  int t = threadIdx.x, lane = t & 63, w = t >> 6, lo = lane & 15, hi = lane >> 4;
  for (int i = t; i < 2048; i += 256) sW[i] = ((const uint4*)pe)[i];
  int eb = blockIdx.x*128 + w*32;
  bf16x8 A[2][4];
  #pragma unroll
  for (int rt = 0; rt < 2; ++rt){
    int er = min(eb + rt*16 + lo, E-1);
    #pragma unroll
    for (int ks = 0; ks < 4; ++ks){
      const float* p = &eattr[(size_t)er*128 + ks*32 + hi*8];
      float4 v0 = *(const float4*)p, v1 = *(const float4*)(p+4);
      FragU u;
      u.b[0]=(__bf16)v0.x; u.b[1]=(__bf16)v0.y; u.b[2]=(__bf16)v0.z; u.b[3]=(__bf16)v0.w;
      u.b[4]=(__bf16)v1.x; u.b[5]=(__bf16)v1.y; u.b[6]=(__bf16)v1.z; u.b[7]=(__bf16)v1.w;
      A[rt][ks] = u.b;
    }
  }
  __syncthreads();
  f32x4 acc[2][8];
  #pragma unroll
  for (int rt = 0; rt < 2; ++rt)
    #pragma unroll
    for (int ct = 0; ct < 8; ++ct) acc[rt][ct] = (f32x4)(0.f);
  #pragma unroll
  for (int ks = 0; ks < 4; ++ks){
    #pragma unroll
    for (int ct = 0; ct < 8; ++ct){
      FragU bu; bu.q = sW[(ct*4 + ks)*64 + lane];
      acc[0][ct] = __builtin_amdgcn_mfma_f32_16x16x32_bf16(A[0][ks], bu.b, acc[0][ct], 0, 0, 0);
      acc[1][ct] = __builtin_amdgcn_mfma_f32_16x16x32_bf16(A[1][ks], bu.b, acc[1][ct], 0, 0, 0);
    }
  }
  float beL[8], atL[8];
  #pragma unroll
  for (int ct = 0; ct < 8; ++ct){ beL[ct] = be[ct*16 + lo]; atL[ct] = att[ct*16 + lo]; }
  #pragma unroll
  for (int rt = 0; rt < 2; ++rt){
    #pragma unroll
    for (int j = 0; j < 4; ++j){
      int e = eb + rt*16 + hi*4 + j;
      int ec = min(e, E-1);
      int s_ = src[ec], d_ = dst[ec];
      const float* xlp = &xlxr[(size_t)s_*256];
      const float* xrp = &xlxr[(size_t)d_*256 + 128];
      float qh[4];
      #pragma unroll
      for (int h = 0; h < 4; ++h){
        float p = 0.f;
        #pragma unroll
        for (int u = 0; u < 2; ++u){
          int ct = 2*h + u, c = ct*16 + lo;
          float m = acc[rt][ct][j] + beL[ct] + xlp[c] + xrp[c];
          m = (m > 0.f) ? m : 0.2f*m;
          p = fmaf(m, atL[ct], p);
        }
        p += __shfl_xor(p, 1); p += __shfl_xor(p, 2);
        p += __shfl_xor(p, 4); p += __shfl_xor(p, 8);
        qh[h] = p;
      }
      if (lo == 0 && e < E)
        *(float4*)&elog[(size_t)e*4] = make_float4(qh[0], qh[1], qh[2], qh[3]);
    }
  }
}

// ---------- K5: fused per-node segment softmax + aggregation + bias ----------
// one wave per node; lane owns cols (lane, lane+64); heads selected by lane&32
__launch_bounds__(256)
__global__ void k_gat_agg(const float* __restrict__ elog, const int* __restrict__ rowptr,
                          const int* __restrict__ eids, const int* __restrict__ src,
                          const float* __restrict__ xlxr, const float* __restrict__ bias,
                          float* __restrict__ xnew, int n){
  int nd = (blockIdx.x*256 + threadIdx.x) >> 6;
  int lane = threadIdx.x & 63;
  if (nd >= n) return;
  int beg = rowptr[nd], end = rowptr[nd+1];
  bool hsel = (lane & 32) != 0;
  float m0 = -INFINITY, m1 = -INFINITY;
  for (int i = beg; i < end; ++i){
    float4 lv = *(const float4*)&elog[(size_t)eids[i]*4];
    float l0 = hsel ? lv.y : lv.x, l1 = hsel ? lv.w : lv.z;
    m0 = fmaxf(m0, l0); m1 = fmaxf(m1, l1);
  }
  float d0 = 0.f, d1 = 0.f;
  for (int i = beg; i < end; ++i){
    float4 lv = *(const float4*)&elog[(size_t)eids[i]*4];
    float l0 = hsel ? lv.y : lv.x, l1 = hsel ? lv.w : lv.z;
    d0 += __expf(l0 - m0); d1 += __expf(l1 - m1);
  }
  float r0 = 1.f/(d0 + 1e-16f), r1 = 1.f/(d1 + 1e-16f);
  float a0 = 0.f, a1 = 0.f;
  int c0 = lane, c1 = lane + 64;
  for (int i = beg; i < end; ++i){
    int e = eids[i];
    float4 lv = *(const float4*)&elog[(size_t)e*4];
    float l0 = hsel ? lv.y : lv.x, l1 = hsel ? lv.w : lv.z;
    float al0 = __expf(l0 - m0)*r0, al1 = __expf(l1 - m1)*r1;
    const float* xp = &xlxr[(size_t)src[e]*256];
    a0 = fmaf(al0, xp[c0], a0);
    a1 = fmaf(al1, xp[c1], a1);
  }
  xnew[(size_t)nd*128 + c0] = a0 + bias[c0];
  xnew[(size_t)nd*128 + c1] = a1 + bias[c1];
}

// ---------- K7: edge MLP (MFMA): gather -> in-register LN -> ReLU -> GEMM -> residual ----------
__launch_bounds__(512)
__global__ void k_edge_mlp(const float* __restrict__ xnew, const int* __restrict__ src,
                           const int* __restrict__ dst, const float* __restrict__ eattr,
                           const unsigned short* __restrict__ pm, const float* __restrict__ bmlp,
                           const float* __restrict__ lng, const float* __restrict__ lnb,
                           float* __restrict__ out, int E){
  __shared__ uint4 sW[4096];
  int t = threadIdx.x, lane = t & 63, w = t >> 6, lo = lane & 15, hi = lane >> 4;
  for (int i = t; i < 4096; i += 512) sW[i] = ((const uint4*)pm)[i];
  int e  = blockIdx.x*128 + w*16 + lo;
  int ec = min(e, E-1);
  int s_ = src[ec], d_ = dst[ec];
  const float* srow = &xnew[(size_t)s_*128];
  const float* drow = &xnew[(size_t)d_*128];
  float raw[8][8];
  #pragma unroll
  for (int ks = 0; ks < 4; ++ks){
    const float* p = &srow[ks*32 + hi*8];
    float4 v0 = *(const float4*)p, v1 = *(const float4*)(p+4);
    raw[ks][0]=v0.x; raw[ks][1]=v0.y; raw[ks][2]=v0.z; raw[ks][3]=v0.w;
    raw[ks][4]=v1.x; raw[ks][5]=v1.y; raw[ks][6]=v1.z; raw[ks][7]=v1.w;
  }
  #pragma unroll
  for (int ks = 4; ks < 8; ++ks){
    const float* p = &drow[(ks-4)*32 + hi*8];
    float4 v0 = *(const float4*)p, v1 = *(const float4*)(p+4);
    raw[ks][0]=v0.x; raw[ks][1]=v0.y; raw[ks][2]=v0.z; raw[ks][3]=v0.w;
    raw[ks][4]=v1.x; raw[ks][5]=v1.y; raw[ks][6]=v1.z; raw[ks][7]=v1.w;
  }
  float s = 0.f, ss = 0.f;
  #pragma unroll
  for (int ks = 0; ks < 8; ++ks)
    #pragma unroll
    for (int j = 0; j < 8; ++j){ float v = raw[ks][j]; s += v; ss = fmaf(v, v, ss); }
  s  += __shfl_xor(s, 16);  s  += __shfl_xor(s, 32);
  ss += __shfl_xor(ss, 16); ss += __shfl_xor(ss, 32);
  float mean = s * (1.f/256.f);
  float var  = ss * (1.f/256.f) - mean*mean;
  float rstd = rsqrtf(var + 1e-5f);
  bf16x8 A[8];
  #pragma unroll
  for (int ks = 0; ks < 8; ++ks){
    int cb = ks*32 + hi*8;
    float4 ga = *(const float4*)&lng[cb], gb = *(const float4*)&lng[cb+4];
    float4 ba = *(const float4*)&lnb[cb], bb = *(const float4*)&lnb[cb+4];
    FragU u;
    #pragma unroll
    for (int j = 0; j < 4; ++j){
      float v = fmaxf(fmaf((raw[ks][j] - mean)*rstd, fc(ga,j), fc(ba,j)), 0.f);
      u.b[j] = (__bf16)v;
    }
    #pragma unroll
    for (int j = 0; j < 4; ++j){
      float v = fmaxf(fmaf((raw[ks][j+4] - mean)*rstd, fc(gb,j), fc(bb,j)), 0.f);
      u.b[j+4] = (__bf16)v;
    }
    A[ks] = u.b;
  }
  __syncthreads();
  f32x4 acc[8];
  #pragma unroll
  for (int ct = 0; ct < 8; ++ct) acc[ct] = (f32x4)(0.f);
  #pragma unroll
  for (int ks = 0; ks < 8; ++ks){
    #pragma unroll
    for (int ct = 0; ct < 8; ++ct){
      FragU bu; bu.q = sW[(ct*8 + ks)*64 + lane];
      acc[ct] = __builtin_amdgcn_mfma_f32_16x16x32_bf16(A[ks], bu.b, acc[ct], 0, 0, 0);
    }
  }
  float bmL[8];
  #pragma unroll
  for (int ct = 0; ct < 8; ++ct) bmL[ct] = bmlp[ct*16 + lo];
  #pragma unroll
  for (int j = 0; j < 4; ++j){
    int e2 = blockIdx.x*128 + w*16 + hi*4 + j;
    if (e2 < E){
      #pragma unroll
      for (int ct = 0; ct < 8; ++ct){
        int c = ct*16 + lo;
        out[(size_t)e2*128 + c] = acc[ct][j] + bmL[ct] + eattr[(size_t)e2*128 + c];
      }
    }
  }
}

// ---------- launcher ----------
extern "C" void kernel_launch(void* const* d_in, const int* in_sizes, int n_in,
                              void* d_out, int out_size, void* d_ws, size_t ws_size,
                              hipStream_t stream){
  const float* x     = (const float*)d_in[0];
  const int*   eidx  = (const int*)  d_in[1];
  const float* eattr = (const float*)d_in[2];
  const float* Wl    = (const float*)d_in[3];
  const float* bl    = (const float*)d_in[4];
  const float* Wr    = (const float*)d_in[5];
  const float* br    = (const float*)d_in[6];
  const float* We    = (const float*)d_in[7];
  const float* be    = (const float*)d_in[8];
  const float* att   = (const float*)d_in[9];
  const float* bias  = (const float*)d_in[10];
  const float* lng   = (const float*)d_in[11];
  const float* lnb   = (const float*)d_in[12];
  const float* Wmlp  = (const float*)d_in[13];
  const float* bmlp  = (const float*)d_in[14];

  int n = in_sizes[0] / 128;
  int E = in_sizes[2] / 128;
  const int* src = eidx;
  const int* dst = eidx + E;

  char* ws = (char*)d_ws;
  size_t off = 0;
  int* cnt    = (int*)(ws + off); off += (size_t)n*4;
  size_t zbytes = off;                       // only cnt needs zeroing
  int* rowptr = (int*)(ws + off); off += (size_t)(n+1)*4;
  int* cursor = (int*)(ws + off); off += (size_t)(n+1)*4;
  int* eids   = (int*)(ws + off); off += (size_t)E*4;
  float* xlxr = (float*)(ws + off); off += (size_t)n*256*4;
  float* elog = (float*)(ws + off); off += (size_t)E*4*4;
  unsigned short* plr = (unsigned short*)(ws + off); off += 32768*2;
  unsigned short* pe  = (unsigned short*)(ws + off); off += 16384*2;
  unsigned short* pm  = (unsigned short*)(ws + off); off += 32768*2;

  float* xnew_out = (float*)d_out;
  float* eout     = (float*)d_out + (size_t)n*128;

  hipMemsetAsync(ws, 0, zbytes, stream);
  k_pack       <<<128, 256, 0, stream>>>(Wl, Wr, We, Wmlp, plr, pe, pm);
  k_hist       <<<(E + 255)/256, 256, 0, stream>>>(dst, cnt, E);
  k_scan       <<<1, 1024, 0, stream>>>(cnt, rowptr, cursor, n);
  k_scatter    <<<(E + 255)/256, 256, 0, stream>>>(dst, cursor, eids, E);
  k_node_linear<<<(n + 63)/64, 256, 0, stream>>>(x, bl, br, plr, xlxr, n);
  k_edge_logits<<<(E + 127)/128, 256, 0, stream>>>(eattr, src, dst, pe, be, att, xlxr, elog, E);
  k_gat_agg    <<<(n + 3)/4, 256, 0, stream>>>(elog, rowptr, eids, src, xlxr, bias, xnew_out, n);
  k_edge_mlp   <<<(E + 127)/128, 512, 0, stream>>>(xnew_out, src, dst, eattr, pm, bmlp, lng, lnb, eout, E);
}

// Round 4
// 553.188 us; speedup vs baseline: 11.9044x; 1.2106x over previous
//
#include <hip/hip_runtime.h>
#include <math.h>

typedef float  f32x4  __attribute__((ext_vector_type(4)));
typedef __bf16 bf16x8 __attribute__((ext_vector_type(8)));

union FragU { uint4 q; bf16x8 b; };

__device__ inline float fc(const float4& v, int k){
  return k==0 ? v.x : k==1 ? v.y : k==2 ? v.z : v.w;
}

// ---------- K0: pack weights to bf16 in MFMA B-fragment order ----------
// frag idx: (((ct*KS + ks)*64 + lane)*8 + j) ; k = ks*32 + (lane>>4)*8 + j ; c = ct*16 + (lane&15)
__global__ void k_pack(const float* __restrict__ Wl, const float* __restrict__ Wr,
                       const float* __restrict__ We, const float* __restrict__ Wm,
                       unsigned short* plr, unsigned short* pe, unsigned short* pm){
  int t = blockIdx.x * 256 + threadIdx.x;
  if (t < 32768){
    int j = t & 7, lane = (t >> 3) & 63, ks = (t >> 9) & 3, ct = t >> 11;
    int k = ks*32 + (lane >> 4)*8 + j, c = ct*16 + (lane & 15);
    float v = (c < 128) ? Wl[k*128 + c] : Wr[k*128 + (c - 128)];
    __bf16 b = (__bf16)v; plr[t] = *(unsigned short*)&b;
  }
  if (t < 16384){
    int j = t & 7, lane = (t >> 3) & 63, ks = (t >> 9) & 3, ct = t >> 11;
    int k = ks*32 + (lane >> 4)*8 + j, c = ct*16 + (lane & 15);
    __bf16 b = (__bf16)We[k*128 + c]; pe[t] = *(unsigned short*)&b;
  }
  if (t < 32768){
    int j = t & 7, lane = (t >> 3) & 63, ks = (t >> 9) & 7, ct = t >> 12;
    int k = ks*32 + (lane >> 4)*8 + j, c = ct*16 + (lane & 15);
    __bf16 b = (__bf16)Wm[k*128 + c]; pm[t] = *(unsigned short*)&b;
  }
}

// ---------- CSR build: histogram -> 3-phase scan -> scatter ----------
__global__ void k_hist(const int* __restrict__ dst, int* __restrict__ cnt, int E){
  int e = blockIdx.x*256 + threadIdx.x;
  if (e < E) atomicAdd(&cnt[dst[e]], 1);
}

// phase 1: per-block (1024 elems) exclusive prefix + block sums
__global__ void k_scan1(const int* __restrict__ cnt, int* __restrict__ pre,
                        int* __restrict__ bsum, int n){
  __shared__ int wsum[4];
  int t = threadIdx.x, lane = t & 63, w = t >> 6;
  int base = blockIdx.x*1024 + t*4;
  int v[4]; int loc = 0;
  #pragma unroll
  for (int j = 0; j < 4; ++j){ v[j] = (base+j < n) ? cnt[base+j] : 0; loc += v[j]; }
  int incl = loc;
  #pragma unroll
  for (int o = 1; o < 64; o <<= 1){
    int u = __shfl_up(incl, o);
    if (lane >= o) incl += u;
  }
  if (lane == 63) wsum[w] = incl;
  __syncthreads();
  int wbase = 0;
  #pragma unroll
  for (int ww = 0; ww < 4; ++ww) if (ww < w) wbase += wsum[ww];
  int run = wbase + incl - loc;
  #pragma unroll
  for (int j = 0; j < 4; ++j){ if (base+j < n) pre[base+j] = run; run += v[j]; }
  if (t == 255) bsum[blockIdx.x] = wbase + incl;
}

// phase 2: single wave scans block sums (nb <= 64)
__global__ void k_scan2(const int* __restrict__ bsum, int* __restrict__ boff, int nb){
  int t = threadIdx.x;
  int v = (t < nb) ? bsum[t] : 0;
  int incl = v;
  #pragma unroll
  for (int o = 1; o < 64; o <<= 1){
    int u = __shfl_up(incl, o);
    if (t >= o) incl += u;
  }
  if (t < nb) boff[t] = incl - v;
  if (t == nb-1) boff[nb] = incl;
}

// phase 3: add block offsets, write rowptr + cursor
__global__ void k_scan3(const int* __restrict__ pre, const int* __restrict__ boff,
                        int* __restrict__ rowptr, int* __restrict__ cursor, int n, int nb){
  int i = blockIdx.x*256 + threadIdx.x;
  if (i < n){
    int r = pre[i] + boff[blockIdx.x >> 2];
    rowptr[i] = r; cursor[i] = r;
  }
  if (i == 0) rowptr[n] = boff[nb];
}

__global__ void k_scatter(const int* __restrict__ dst, int* __restrict__ cursor,
                          int* __restrict__ eids, int E){
  int e = blockIdx.x*256 + threadIdx.x;
  if (e < E){ int p = atomicAdd(&cursor[dst[e]], 1); eids[p] = e; }
}

// ---------- K1: xlxr = [x@W_l+b_l | x@W_r+b_r]  (MFMA) ----------
__launch_bounds__(256)
__global__ void k_node_linear(const float* __restrict__ x, const float* __restrict__ bl,
                              const float* __restrict__ br, const unsigned short* __restrict__ plr,
                              float* __restrict__ xlxr, int n){
  __shared__ uint4 sW[4096];
  int t = threadIdx.x, lane = t & 63, w = t >> 6, lo = lane & 15, hi = lane >> 4;
  for (int i = t; i < 4096; i += 256) sW[i] = ((const uint4*)plr)[i];
  int row = blockIdx.x*64 + w*16 + lo;
  int rc  = min(row, n-1);
  bf16x8 A[4];
  #pragma unroll
  for (int ks = 0; ks < 4; ++ks){
    const float* p = &x[(size_t)rc*128 + ks*32 + hi*8];
    float4 v0 = *(const float4*)p, v1 = *(const float4*)(p+4);
    FragU u;
    u.b[0]=(__bf16)v0.x; u.b[1]=(__bf16)v0.y; u.b[2]=(__bf16)v0.z; u.b[3]=(__bf16)v0.w;
    u.b[4]=(__bf16)v1.x; u.b[5]=(__bf16)v1.y; u.b[6]=(__bf16)v1.z; u.b[7]=(__bf16)v1.w;
    A[ks] = u.b;
  }
  __syncthreads();
  f32x4 acc[16];
  #pragma unroll
  for (int ct = 0; ct < 16; ++ct) acc[ct] = (f32x4)(0.f);
  #pragma unroll
  for (int ks = 0; ks < 4; ++ks){
    #pragma unroll
    for (int ct = 0; ct < 16; ++ct){
      FragU bu; bu.q = sW[(ct*4 + ks)*64 + lane];
      acc[ct] = __builtin_amdgcn_mfma_f32_16x16x32_bf16(A[ks], bu.b, acc[ct], 0, 0, 0);
    }
  }
  float biasL[16];
  #pragma unroll
  for (int ct = 0; ct < 16; ++ct){
    int c = ct*16 + lo;
    biasL[ct] = (c < 128) ? bl[c] : br[c - 128];
  }
  #pragma unroll
  for (int j = 0; j < 4; ++j){
    int nd = blockIdx.x*64 + w*16 + hi*4 + j;
    if (nd < n){
      #pragma unroll
      for (int ct = 0; ct < 16; ++ct)
        xlxr[(size_t)nd*256 + ct*16 + lo] = acc[ct][j] + biasL[ct];
    }
  }
}

// ---------- K2: ee GEMM (MFMA) + attention logits ----------
// 8 waves x 16 edges = 128 edges/block; N=128 (8 ct), K=128 (4 ks)
__launch_bounds__(512)
__global__ void k_edge_logits(const float* __restrict__ eattr, const int* __restrict__ src,
                              const int* __restrict__ dst, const unsigned short* __restrict__ pe,
                              const float* __restrict__ be, const float* __restrict__ att,
                              const float* __restrict__ xlxr, float* __restrict__ elog, int E){
  __shared__ uint4 sW[2048];  // 32KB
  int t = threadIdx.x, lane = t & 63, w = t >> 6, lo = lane & 15, hi = lane >> 4;
  for (int i = t; i < 2048; i += 512) sW[i] = ((const uint4*)pe)[i];
  int eb = blockIdx.x*128 + w*16;
  int er = min(eb + lo, E-1);
  bf16x8 A[4];
  #pragma unroll
  for (int ks = 0; ks < 4; ++ks){
    const float* p = &eattr[(size_t)er*128 + ks*32 + hi*8];
    float4 v0 = *(const float4*)p, v1 = *(const float4*)(p+4);
    FragU u;
    u.b[0]=(__bf16)v0.x; u.b[1]=(__bf16)v0.y; u.b[2]=(__bf16)v0.z; u.b[3]=(__bf16)v0.w;
    u.b[4]=(__bf16)v1.x; u.b[5]=(__bf16)v1.y; u.b[6]=(__bf16)v1.z; u.b[7]=(__bf16)v1.w;
    A[ks] = u.b;
  }
  __syncthreads();
  f32x4 acc[8];
  #pragma unroll
  for (int ct = 0; ct < 8; ++ct) acc[ct] = (f32x4)(0.f);
  #pragma unroll
  for (int ks = 0; ks < 4; ++ks){
    #pragma unroll
    for (int ct = 0; ct < 8; ++ct){
      FragU bu; bu.q = sW[(ct*4 + ks)*64 + lane];
      acc[ct] = __builtin_amdgcn_mfma_f32_16x16x32_bf16(A[ks], bu.b, acc[ct], 0, 0, 0);
    }
  }
  float beL[8], atL[8];
  #pragma unroll
  for (int ct = 0; ct < 8; ++ct){ beL[ct] = be[ct*16 + lo]; atL[ct] = att[ct*16 + lo]; }
  #pragma unroll
  for (int j = 0; j < 4; ++j){
    int e = eb + hi*4 + j;
    int ec = min(e, E-1);
    int s_ = src[ec], d_ = dst[ec];
    const float* xlp = &xlxr[(size_t)s_*256];
    const float* xrp = &xlxr[(size_t)d_*256 + 128];
    float qh[4];
    #pragma unroll
    for (int h = 0; h < 4; ++h){
      float p = 0.f;
      #pragma unroll
      for (int u = 0; u < 2; ++u){
        int ct = 2*h + u, c = ct*16 + lo;
        float m = acc[ct][j] + beL[ct] + xlp[c] + xrp[c];
        m = (m > 0.f) ? m : 0.2f*m;
        p = fmaf(m, atL[ct], p);
      }
      p += __shfl_xor(p, 1); p += __shfl_xor(p, 2);
      p += __shfl_xor(p, 4); p += __shfl_xor(p, 8);
      qh[h] = p;
    }
    if (lo == 0 && e < E)
      *(float4*)&elog[(size_t)e*4] = make_float4(qh[0], qh[1], qh[2], qh[3]);
  }
}

// ---------- K5: fused per-node segment softmax (online) + aggregation + bias ----------
__launch_bounds__(256)
__global__ void k_gat_agg(const float* __restrict__ elog, const int* __restrict__ rowptr,
                          const int* __restrict__ eids, const int* __restrict__ src,
                          const float* __restrict__ xlxr, const float* __restrict__ bias,
                          float* __restrict__ xnew, int n){
  int nd = (blockIdx.x*256 + threadIdx.x) >> 6;
  int lane = threadIdx.x & 63;
  if (nd >= n) return;
  int beg = rowptr[nd], end = rowptr[nd+1];
  bool hsel = (lane & 32) != 0;
  float m0 = -INFINITY, m1 = -INFINITY, d0 = 0.f, d1 = 0.f;
  for (int i = beg; i < end; ++i){
    float4 lv = *(const float4*)&elog[(size_t)eids[i]*4];
    float l0 = hsel ? lv.y : lv.x, l1 = hsel ? lv.w : lv.z;
    float nm0 = fmaxf(m0, l0), nm1 = fmaxf(m1, l1);
    d0 = d0*__expf(m0 - nm0) + __expf(l0 - nm0);
    d1 = d1*__expf(m1 - nm1) + __expf(l1 - nm1);
    m0 = nm0; m1 = nm1;
  }
  float r0 = 1.f/(d0 + 1e-16f), r1 = 1.f/(d1 + 1e-16f);
  float a0 = 0.f, a1 = 0.f;
  int c0 = lane, c1 = lane + 64;
  for (int i = beg; i < end; ++i){
    int e = eids[i];
    float4 lv = *(const float4*)&elog[(size_t)e*4];
    float l0 = hsel ? lv.y : lv.x, l1 = hsel ? lv.w : lv.z;
    float al0 = __expf(l0 - m0)*r0, al1 = __expf(l1 - m1)*r1;
    const float* xp = &xlxr[(size_t)src[e]*256];
    a0 = fmaf(al0, xp[c0], a0);
    a1 = fmaf(al1, xp[c1], a1);
  }
  xnew[(size_t)nd*128 + c0] = a0 + bias[c0];
  xnew[(size_t)nd*128 + c1] = a1 + bias[c1];
}

// ---------- K7: edge MLP (MFMA): gather -> in-register LN -> ReLU -> GEMM -> residual ----------
// 8 waves x 16 edges = 128 edges/block; 32KB LDS (K staged in 2 halves); bf16 raw storage
__launch_bounds__(512)
__global__ void k_edge_mlp(const float* __restrict__ xnew, const int* __restrict__ src,
                           const int* __restrict__ dst, const float* __restrict__ eattr,
                           const unsigned short* __restrict__ pm, const float* __restrict__ bmlp,
                           const float* __restrict__ lng, const float* __restrict__ lnb,
                           float* __restrict__ out, int E){
  __shared__ uint4 sW[2048];  // 32KB: one K-half of W_mlp
  const uint4* pm_q = (const uint4*)pm;
  int t = threadIdx.x, lane = t & 63, w = t >> 6, lo = lane & 15, hi = lane >> 4;
  // stage K-half 0 early (overlaps gather/LN below)
  for (int i = t; i < 2048; i += 512) sW[i] = pm_q[i + ((i>>8)<<8)];
  int e  = blockIdx.x*128 + w*16 + lo;
  int ec = min(e, E-1);
  int s_ = src[ec], d_ = dst[ec];
  const float* srow = &xnew[(size_t)s_*128];
  const float* drow = &xnew[(size_t)d_*128];
  // gather rows; stats from exact f32; store raw as bf16 (register relief)
  bf16x8 af[8];
  float s = 0.f, ss = 0.f;
  #pragma unroll
  for (int ks = 0; ks < 8; ++ks){
    const float* row = (ks < 4) ? srow : drow;
    const float* p = &row[(ks & 3)*32 + hi*8];
    float4 v0 = *(const float4*)p, v1 = *(const float4*)(p+4);
    s += v0.x+v0.y+v0.z+v0.w + v1.x+v1.y+v1.z+v1.w;
    ss = fmaf(v0.x,v0.x, fmaf(v0.y,v0.y, fmaf(v0.z,v0.z, fmaf(v0.w,v0.w, ss))));
    ss = fmaf(v1.x,v1.x, fmaf(v1.y,v1.y, fmaf(v1.z,v1.z, fmaf(v1.w,v1.w, ss))));
    FragU u;
    u.b[0]=(__bf16)v0.x; u.b[1]=(__bf16)v0.y; u.b[2]=(__bf16)v0.z; u.b[3]=(__bf16)v0.w;
    u.b[4]=(__bf16)v1.x; u.b[5]=(__bf16)v1.y; u.b[6]=(__bf16)v1.z; u.b[7]=(__bf16)v1.w;
    af[ks] = u.b;
  }
  s  += __shfl_xor(s, 16);  s  += __shfl_xor(s, 32);
  ss += __shfl_xor(ss, 16); ss += __shfl_xor(ss, 32);
  float mean = s * (1.f/256.f);
  float var  = ss * (1.f/256.f) - mean*mean;
  float rstd = rsqrtf(var + 1e-5f);
  // normalize + affine + relu in place
  #pragma unroll
  for (int ks = 0; ks < 8; ++ks){
    int cb = ks*32 + hi*8;
    float4 ga = *(const float4*)&lng[cb], gb = *(const float4*)&lng[cb+4];
    float4 ba = *(const float4*)&lnb[cb], bb = *(const float4*)&lnb[cb+4];
    FragU u; u.b = af[ks];
    #pragma unroll
    for (int j = 0; j < 4; ++j){
      float v = fmaxf(fmaf(((float)u.b[j] - mean)*rstd, fc(ga,j), fc(ba,j)), 0.f);
      u.b[j] = (__bf16)v;
    }
    #pragma unroll
    for (int j = 0; j < 4; ++j){
      float v = fmaxf(fmaf(((float)u.b[j+4] - mean)*rstd, fc(gb,j), fc(bb,j)), 0.f);
      u.b[j+4] = (__bf16)v;
    }
    af[ks] = u.b;
  }
  f32x4 acc[8];
  #pragma unroll
  for (int ct = 0; ct < 8; ++ct) acc[ct] = (f32x4)(0.f);
  __syncthreads();
  // MFMA K-half 0
  #pragma unroll
  for (int ksh = 0; ksh < 4; ++ksh){
    #pragma unroll
    for (int ct = 0; ct < 8; ++ct){
      FragU bu; bu.q = sW[(ct*4 + ksh)*64 + lane];
      acc[ct] = __builtin_amdgcn_mfma_f32_16x16x32_bf16(af[ksh], bu.b, acc[ct], 0, 0, 0);
    }
  }
  __syncthreads();
  // stage K-half 1
  for (int i = t; i < 2048; i += 512) sW[i] = pm_q[i + ((i>>8)<<8) + 256];
  __syncthreads();
  #pragma unroll
  for (int ksh = 0; ksh < 4; ++ksh){
    #pragma unroll
    for (int ct = 0; ct < 8; ++ct){
      FragU bu; bu.q = sW[(ct*4 + ksh)*64 + lane];
      acc[ct] = __builtin_amdgcn_mfma_f32_16x16x32_bf16(af[4+ksh], bu.b, acc[ct], 0, 0, 0);
    }
  }
  float bmL[8];
  #pragma unroll
  for (int ct = 0; ct < 8; ++ct) bmL[ct] = bmlp[ct*16 + lo];
  #pragma unroll
  for (int j = 0; j < 4; ++j){
    int e2 = blockIdx.x*128 + w*16 + hi*4 + j;
    if (e2 < E){
      #pragma unroll
      for (int ct = 0; ct < 8; ++ct){
        int c = ct*16 + lo;
        out[(size_t)e2*128 + c] = acc[ct][j] + bmL[ct] + eattr[(size_t)e2*128 + c];
      }
    }
  }
}

// ---------- launcher ----------
extern "C" void kernel_launch(void* const* d_in, const int* in_sizes, int n_in,
                              void* d_out, int out_size, void* d_ws, size_t ws_size,
                              hipStream_t stream){
  const float* x     = (const float*)d_in[0];
  const int*   eidx  = (const int*)  d_in[1];
  const float* eattr = (const float*)d_in[2];
  const float* Wl    = (const float*)d_in[3];
  const float* bl    = (const float*)d_in[4];
  const float* Wr    = (const float*)d_in[5];
  const float* br    = (const float*)d_in[6];
  const float* We    = (const float*)d_in[7];
  const float* be    = (const float*)d_in[8];
  const float* att   = (const float*)d_in[9];
  const float* bias  = (const float*)d_in[10];
  const float* lng   = (const float*)d_in[11];
  const float* lnb   = (const float*)d_in[12];
  const float* Wmlp  = (const float*)d_in[13];
  const float* bmlp  = (const float*)d_in[14];

  int n = in_sizes[0] / 128;
  int E = in_sizes[2] / 128;
  const int* src = eidx;
  const int* dst = eidx + E;
  int nb = (n + 1023) / 1024;

  char* ws = (char*)d_ws;
  size_t off = 0;
  int* cnt    = (int*)(ws + off); off += (size_t)n*4;
  size_t zbytes = off;                       // only cnt needs zeroing
  int* pre    = (int*)(ws + off); off += (size_t)n*4;
  int* rowptr = (int*)(ws + off); off += (size_t)(n+1)*4;
  int* cursor = (int*)(ws + off); off += (size_t)(n+1)*4;
  int* bsum   = (int*)(ws + off); off += (size_t)nb*4;
  int* boff   = (int*)(ws + off); off += (size_t)(nb+1)*4;
  int* eids   = (int*)(ws + off); off += (size_t)E*4;
  float* xlxr = (float*)(ws + off); off += (size_t)n*256*4;
  float* elog = (float*)(ws + off); off += (size_t)E*4*4;
  unsigned short* plr = (unsigned short*)(ws + off); off += 32768*2;
  unsigned short* pe  = (unsigned short*)(ws + off); off += 16384*2;
  unsigned short* pm  = (unsigned short*)(ws + off); off += 32768*2;

  float* xnew_out = (float*)d_out;
  float* eout     = (float*)d_out + (size_t)n*128;

  hipMemsetAsync(ws, 0, zbytes, stream);
  k_pack       <<<128, 256, 0, stream>>>(Wl, Wr, We, Wmlp, plr, pe, pm);
  k_hist       <<<(E + 255)/256, 256, 0, stream>>>(dst, cnt, E);
  k_scan1      <<<nb, 256, 0, stream>>>(cnt, pre, bsum, n);
  k_scan2      <<<1, 64, 0, stream>>>(bsum, boff, nb);
  k_scan3      <<<nb*4, 256, 0, stream>>>(pre, boff, rowptr, cursor, n, nb);
  k_scatter    <<<(E + 255)/256, 256, 0, stream>>>(dst, cursor, eids, E);
  k_node_linear<<<(n + 63)/64, 256, 0, stream>>>(x, bl, br, plr, xlxr, n);
  k_edge_logits<<<(E + 127)/128, 512, 0, stream>>>(eattr, src, dst, pe, be, att, xlxr, elog, E);
  k_gat_agg    <<<(n + 3)/4, 256, 0, stream>>>(elog, rowptr, eids, src, xlxr, bias, xnew_out, n);
  k_edge_mlp   <<<(E + 127)/128, 512, 0, stream>>>(xnew_out, src, dst, eattr, pm, bmlp, lng, lnb, eout, E);
}